// Round 3
// baseline (49.953 us; speedup 1.0000x reference)
//
#include <hip/hip_runtime.h>

// y[b,u] = clip( sum_d x[b,d] ** exp2(w[d,u]) + bias[u], 0, 1 )
// inten = exp2( e[d,u] * lx[b,d] ),  e = exp2(w), lx = log2(x).
// R2: LDS pipe (shared per-CU) was the bottleneck (288 vs 128 cyc/d-step).
//     -> precompute lxT[d][b], eT[u][d] in ws; hot loop is register-only:
//     lane->b (coalesced lx dword loads), wave-uniform e float4 loads,
//     pk_mul + exp2 + pk_add. Trans floor ~13.7us.

#define NU 4    // u's per wave
#define DR 16   // d-chunk in registers

typedef float f2 __attribute__((ext_vector_type(2)));

// ---- Kernel A: fused transpose + transcendental precompute ----
// lxT[d][b] = log2(x[b][d])   (D x B)
// eT [u][d] = exp2(w[d][u])   (U x D)
__global__ __launch_bounds__(256)
void precompute_kernel(const float* __restrict__ x, const float* __restrict__ w,
                       float* __restrict__ lxT, float* __restrict__ eT,
                       int B, int D, int U)
{
    __shared__ float t[32][33];
    const int tid = threadIdx.x;
    const int row0 = tid >> 5;   // 0..7
    const int col  = tid & 31;
    int blk = blockIdx.x;
    const int nlx = (B / 32) * (D / 32);
    if (blk < nlx) {
        const int bt = blk / (D / 32);
        const int dt = blk % (D / 32);
        const int b0 = bt * 32, d0 = dt * 32;
        #pragma unroll
        for (int k = 0; k < 4; ++k) {
            const int r = row0 + k * 8;
            t[r][col] = __builtin_amdgcn_logf(x[(size_t)(b0 + r) * D + d0 + col]);
        }
        __syncthreads();
        #pragma unroll
        for (int k = 0; k < 4; ++k) {
            const int r = row0 + k * 8;  // d within tile
            lxT[(size_t)(d0 + r) * B + b0 + col] = t[col][r];
        }
    } else {
        blk -= nlx;
        const int dt = blk / (U / 32);
        const int ut = blk % (U / 32);
        const int d0 = dt * 32, u0 = ut * 32;
        #pragma unroll
        for (int k = 0; k < 4; ++k) {
            const int r = row0 + k * 8;  // d within tile
            t[r][col] = __builtin_amdgcn_exp2f(w[(size_t)(d0 + r) * U + u0 + col]);
        }
        __syncthreads();
        #pragma unroll
        for (int k = 0; k < 4; ++k) {
            const int r = row0 + k * 8;  // u within tile
            eT[(size_t)(u0 + r) * D + d0 + col] = t[col][r];
        }
    }
}

// ---- Kernel B: main compute, register-only hot loop ----
__global__ __launch_bounds__(256)
void fuzzy_main(const float* __restrict__ lxT, const float* __restrict__ eT,
                const float* __restrict__ bias, float* __restrict__ out,
                int B, int D, int U)
{
    const int tid  = threadIdx.x;
    const int lane = tid & 63;
    const int wid  = blockIdx.x * 4 + (tid >> 6);
    const int b    = (wid & 31) * 64 + lane;   // 32 b-chunks of 64
    const int u0   = (wid >> 5) * NU;          // U/NU u-chunks

    f2 acc[NU];
    #pragma unroll
    for (int i = 0; i < NU; ++i) acc[i] = (f2){0.f, 0.f};

    for (int d0 = 0; d0 < D; d0 += DR) {
        float lxr[DR];
        #pragma unroll
        for (int dd = 0; dd < DR; ++dd)
            lxr[dd] = lxT[(size_t)(d0 + dd) * B + b];  // coalesced dword

        #pragma unroll
        for (int uu = 0; uu < NU; ++uu) {
            const float4* ep =
                reinterpret_cast<const float4*>(&eT[(size_t)(u0 + uu) * D + d0]);
            float4 e4[DR / 4];
            #pragma unroll
            for (int k = 0; k < DR / 4; ++k) e4[k] = ep[k];  // wave-uniform
            const f2* ef = reinterpret_cast<const f2*>(e4);
            #pragma unroll
            for (int j = 0; j < DR / 2; ++j) {
                f2 lp = {lxr[2 * j], lxr[2 * j + 1]};
                const f2 p = ef[j] * lp;       // v_pk_mul_f32
                f2 r;
                r.x = __builtin_amdgcn_exp2f(p.x);
                r.y = __builtin_amdgcn_exp2f(p.y);
                acc[uu] += r;                  // v_pk_add_f32
            }
        }
    }

    const float4 bv = *reinterpret_cast<const float4*>(&bias[u0]);
    float4 o;
    o.x = fminf(fmaxf(acc[0].x + acc[0].y + bv.x, 0.f), 1.f);
    o.y = fminf(fmaxf(acc[1].x + acc[1].y + bv.y, 0.f), 1.f);
    o.z = fminf(fmaxf(acc[2].x + acc[2].y + bv.z, 0.f), 1.f);
    o.w = fminf(fmaxf(acc[3].x + acc[3].y + bv.w, 0.f), 1.f);
    *reinterpret_cast<float4*>(&out[(size_t)b * U + u0]) = o;
}

// ---- Fallback (R1 kernel) if ws too small ----
#define BT 32
#define UT 32
#define DK 64
__global__ __launch_bounds__(256)
void fuzzy_fallback(const float* __restrict__ x, const float* __restrict__ w,
                    const float* __restrict__ bias, float* __restrict__ out,
                    int B, int D, int U)
{
    __shared__ float lxs[BT][DK + 1];
    __shared__ float es[DK][UT];
    const int tid = threadIdx.x;
    const int c = tid & 7;
    const int r = tid >> 3;
    const int u0 = blockIdx.x * UT;
    const int b0 = blockIdx.y * BT;
    f2 acc0 = {0.f, 0.f}, acc1 = {0.f, 0.f};
    const int lrow = tid >> 4, lcol4 = (tid & 15) * 4;
    const int erow = tid >> 3, ecol4 = (tid & 7) * 4;
    for (int d0 = 0; d0 < D; d0 += DK) {
        #pragma unroll
        for (int p = 0; p < BT / 16; ++p) {
            const int row = p * 16 + lrow;
            const float4 v = *reinterpret_cast<const float4*>(
                &x[(size_t)(b0 + row) * D + d0 + lcol4]);
            lxs[row][lcol4 + 0] = __builtin_amdgcn_logf(v.x);
            lxs[row][lcol4 + 1] = __builtin_amdgcn_logf(v.y);
            lxs[row][lcol4 + 2] = __builtin_amdgcn_logf(v.z);
            lxs[row][lcol4 + 3] = __builtin_amdgcn_logf(v.w);
        }
        #pragma unroll
        for (int p = 0; p < DK / 32; ++p) {
            const int drow = p * 32 + erow;
            const float4 v = *reinterpret_cast<const float4*>(
                &w[(size_t)(d0 + drow) * U + u0 + ecol4]);
            float4 e;
            e.x = __builtin_amdgcn_exp2f(v.x);
            e.y = __builtin_amdgcn_exp2f(v.y);
            e.z = __builtin_amdgcn_exp2f(v.z);
            e.w = __builtin_amdgcn_exp2f(v.w);
            *reinterpret_cast<float4*>(&es[drow][ecol4]) = e;
        }
        __syncthreads();
        #pragma unroll 8
        for (int d = 0; d < DK; ++d) {
            const float lx = lxs[r][d];
            const f2* ep = reinterpret_cast<const f2*>(&es[d][4 * c]);
            const f2 e0 = ep[0], e1 = ep[1];
            const f2 lx2 = {lx, lx};
            const f2 p0 = e0 * lx2, p1 = e1 * lx2;
            f2 t0, t1;
            t0.x = __builtin_amdgcn_exp2f(p0.x);
            t0.y = __builtin_amdgcn_exp2f(p0.y);
            t1.x = __builtin_amdgcn_exp2f(p1.x);
            t1.y = __builtin_amdgcn_exp2f(p1.y);
            acc0 += t0;
            acc1 += t1;
        }
        __syncthreads();
    }
    const float4 bv = *reinterpret_cast<const float4*>(&bias[u0 + 4 * c]);
    float4 o;
    o.x = fminf(fmaxf(acc0.x + bv.x, 0.f), 1.f);
    o.y = fminf(fmaxf(acc0.y + bv.y, 0.f), 1.f);
    o.z = fminf(fmaxf(acc1.x + bv.z, 0.f), 1.f);
    o.w = fminf(fmaxf(acc1.y + bv.w, 0.f), 1.f);
    *reinterpret_cast<float4*>(&out[(size_t)(b0 + r) * U + u0 + 4 * c]) = o;
}

extern "C" void kernel_launch(void* const* d_in, const int* in_sizes, int n_in,
                              void* d_out, int out_size, void* d_ws, size_t ws_size,
                              hipStream_t stream) {
    const float* x = (const float*)d_in[0];
    const float* w = (const float*)d_in[1];
    const float* b = (const float*)d_in[2];
    float* out = (float*)d_out;

    const int U = in_sizes[2];            // 512
    const int D = in_sizes[1] / U;        // 256
    const int B = in_sizes[0] / D;        // 2048

    const size_t need = ((size_t)B * D + (size_t)U * D) * sizeof(float);
    if (ws_size < need) {
        dim3 grid(U / UT, B / BT);
        fuzzy_fallback<<<grid, dim3(256), 0, stream>>>(x, w, b, out, B, D, U);
        return;
    }

    float* lxT = (float*)d_ws;            // [D][B]
    float* eT  = lxT + (size_t)B * D;     // [U][D]

    const int nblkA = (B / 32) * (D / 32) + (D / 32) * (U / 32);  // 640
    precompute_kernel<<<dim3(nblkA), dim3(256), 0, stream>>>(x, w, lxT, eT, B, D, U);

    const int nwaves = (B / 64) * (U / NU);   // 4096
    fuzzy_main<<<dim3(nwaves / 4), dim3(256), 0, stream>>>(lxT, eT, b, out, B, D, U);
}

// Round 4
// 44.775 us; speedup vs baseline: 1.1156x; 1.1156x over previous
//
#include <hip/hip_runtime.h>

// y[b,u] = clip( sum_d x[b,d] ** exp2(w[d,u]) + bias[u], 0, 1 )
// inten = exp2( e[d,u] * lx[b,d] ),  e = exp2(w), lx = log2(x).
// R3: R2 was latency-bound (VALUBusy 45%, nothing saturated): no cross-chunk
//     pipelining. Now: explicit A/B register double-buffer, 4 b's per lane
//     (float4 lx loads), NU=2 u per wave, 64 independent exp2 per chunk.
//     Trans-pipe floor ~13.7us for 2.68e8 v_exp_f32.

#define NU 2    // u's per wave
#define DR 8    // d per chunk

typedef float f4 __attribute__((ext_vector_type(4)));

// ---- Kernel A: fused transpose + transcendental precompute ----
// lxT[d][b] = log2(x[b][d])   (D x B)
// eT [u][d] = exp2(w[d][u])   (U x D)
__global__ __launch_bounds__(256)
void precompute_kernel(const float* __restrict__ x, const float* __restrict__ w,
                       float* __restrict__ lxT, float* __restrict__ eT,
                       int B, int D, int U)
{
    __shared__ float t[32][33];
    const int tid = threadIdx.x;
    const int row0 = tid >> 5;   // 0..7
    const int col  = tid & 31;
    int blk = blockIdx.x;
    const int nlx = (B / 32) * (D / 32);
    if (blk < nlx) {
        const int bt = blk / (D / 32);
        const int dt = blk % (D / 32);
        const int b0 = bt * 32, d0 = dt * 32;
        #pragma unroll
        for (int k = 0; k < 4; ++k) {
            const int r = row0 + k * 8;
            t[r][col] = __builtin_amdgcn_logf(x[(size_t)(b0 + r) * D + d0 + col]);
        }
        __syncthreads();
        #pragma unroll
        for (int k = 0; k < 4; ++k) {
            const int r = row0 + k * 8;  // d within tile
            lxT[(size_t)(d0 + r) * B + b0 + col] = t[col][r];
        }
    } else {
        blk -= nlx;
        const int dt = blk / (U / 32);
        const int ut = blk % (U / 32);
        const int d0 = dt * 32, u0 = ut * 32;
        #pragma unroll
        for (int k = 0; k < 4; ++k) {
            const int r = row0 + k * 8;  // d within tile
            t[r][col] = __builtin_amdgcn_exp2f(w[(size_t)(d0 + r) * U + u0 + col]);
        }
        __syncthreads();
        #pragma unroll
        for (int k = 0; k < 4; ++k) {
            const int r = row0 + k * 8;  // u within tile
            eT[(size_t)(u0 + r) * D + d0 + col] = t[col][r];
        }
    }
}

// ---- Kernel B: main compute, register ping-pong, no LDS ----

#define LOAD_CHUNK(lx, ex0, ex1, c)                               \
    _Pragma("unroll")                                             \
    for (int d = 0; d < DR; ++d)                                  \
        lx[d] = *(const f4*)(lxp + (size_t)((c) * DR + d) * B);   \
    ex0[0] = *(const f4*)(e0p + (c) * DR);                        \
    ex0[1] = *(const f4*)(e0p + (c) * DR + 4);                    \
    ex1[0] = *(const f4*)(e1p + (c) * DR);                        \
    ex1[1] = *(const f4*)(e1p + (c) * DR + 4);

#define DO_PAIR(lx4, es0, es1)                                            \
    {                                                                     \
        const f4 p0 = lx4 * (es0);                                        \
        const f4 p1 = lx4 * (es1);                                        \
        f4 t0, t1;                                                        \
        t0.x = __builtin_amdgcn_exp2f(p0.x);                              \
        t0.y = __builtin_amdgcn_exp2f(p0.y);                              \
        t0.z = __builtin_amdgcn_exp2f(p0.z);                              \
        t0.w = __builtin_amdgcn_exp2f(p0.w);                              \
        t1.x = __builtin_amdgcn_exp2f(p1.x);                              \
        t1.y = __builtin_amdgcn_exp2f(p1.y);                              \
        t1.z = __builtin_amdgcn_exp2f(p1.z);                              \
        t1.w = __builtin_amdgcn_exp2f(p1.w);                              \
        acc0 += t0;                                                       \
        acc1 += t1;                                                       \
    }

#define COMPUTE_CHUNK(lx, ex0, ex1)          \
    DO_PAIR(lx[0], ex0[0].x, ex1[0].x)       \
    DO_PAIR(lx[1], ex0[0].y, ex1[0].y)       \
    DO_PAIR(lx[2], ex0[0].z, ex1[0].z)       \
    DO_PAIR(lx[3], ex0[0].w, ex1[0].w)       \
    DO_PAIR(lx[4], ex0[1].x, ex1[1].x)       \
    DO_PAIR(lx[5], ex0[1].y, ex1[1].y)       \
    DO_PAIR(lx[6], ex0[1].z, ex1[1].z)       \
    DO_PAIR(lx[7], ex0[1].w, ex1[1].w)

__global__ __launch_bounds__(256)
void fuzzy_main(const float* __restrict__ lxT, const float* __restrict__ eT,
                const float* __restrict__ bias, float* __restrict__ out,
                int B, int D, int U)
{
    const int tid  = threadIdx.x;
    const int lane = tid & 63;
    const int wv   = tid >> 6;
    const int u0   = blockIdx.x * NU;                  // block-uniform
    const int b    = blockIdx.y * 1024 + wv * 256 + lane * 4;

    const float* lxp = lxT + b;                        // column of lxT
    const float* e0p = eT + (size_t)u0 * D;
    const float* e1p = e0p + D;

    f4 acc0 = {0.f, 0.f, 0.f, 0.f};
    f4 acc1 = {0.f, 0.f, 0.f, 0.f};

    f4 lxA[DR], lxB[DR];
    f4 eA0[2], eA1[2], eB0[2], eB1[2];

    const int NCH = D / DR;                            // 32

    LOAD_CHUNK(lxA, eA0, eA1, 0)

    for (int i = 0; i < NCH / 2; ++i) {
        const int cB = 2 * i + 1;
        const int cN = (2 * i + 2 < NCH) ? (2 * i + 2) : (NCH - 1);
        LOAD_CHUNK(lxB, eB0, eB1, cB)      // prefetch odd chunk
        COMPUTE_CHUNK(lxA, eA0, eA1)       // compute even chunk 2i
        LOAD_CHUNK(lxA, eA0, eA1, cN)      // prefetch next even chunk
        COMPUTE_CHUNK(lxB, eB0, eB1)       // compute odd chunk 2i+1
    }

    const float bv0 = bias[u0];
    const float bv1 = bias[u0 + 1];
    #pragma unroll
    for (int j = 0; j < 4; ++j) {
        const float o0 = fminf(fmaxf(acc0[j] + bv0, 0.f), 1.f);
        const float o1 = fminf(fmaxf(acc1[j] + bv1, 0.f), 1.f);
        out[(size_t)(b + j) * U + u0]     = o0;
        out[(size_t)(b + j) * U + u0 + 1] = o1;
    }
}

// ---- Fallback (R1 kernel) if ws too small / odd shapes ----
#define BT 32
#define UT 32
#define DK 64
typedef float f2 __attribute__((ext_vector_type(2)));
__global__ __launch_bounds__(256)
void fuzzy_fallback(const float* __restrict__ x, const float* __restrict__ w,
                    const float* __restrict__ bias, float* __restrict__ out,
                    int B, int D, int U)
{
    __shared__ float lxs[BT][DK + 1];
    __shared__ float es[DK][UT];
    const int tid = threadIdx.x;
    const int c = tid & 7;
    const int r = tid >> 3;
    const int u0 = blockIdx.x * UT;
    const int b0 = blockIdx.y * BT;
    f2 acc0 = {0.f, 0.f}, acc1 = {0.f, 0.f};
    const int lrow = tid >> 4, lcol4 = (tid & 15) * 4;
    const int erow = tid >> 3, ecol4 = (tid & 7) * 4;
    for (int d0 = 0; d0 < D; d0 += DK) {
        #pragma unroll
        for (int p = 0; p < BT / 16; ++p) {
            const int row = p * 16 + lrow;
            const float4 v = *reinterpret_cast<const float4*>(
                &x[(size_t)(b0 + row) * D + d0 + lcol4]);
            lxs[row][lcol4 + 0] = __builtin_amdgcn_logf(v.x);
            lxs[row][lcol4 + 1] = __builtin_amdgcn_logf(v.y);
            lxs[row][lcol4 + 2] = __builtin_amdgcn_logf(v.z);
            lxs[row][lcol4 + 3] = __builtin_amdgcn_logf(v.w);
        }
        #pragma unroll
        for (int p = 0; p < DK / 32; ++p) {
            const int drow = p * 32 + erow;
            const float4 v = *reinterpret_cast<const float4*>(
                &w[(size_t)(d0 + drow) * U + u0 + ecol4]);
            float4 e;
            e.x = __builtin_amdgcn_exp2f(v.x);
            e.y = __builtin_amdgcn_exp2f(v.y);
            e.z = __builtin_amdgcn_exp2f(v.z);
            e.w = __builtin_amdgcn_exp2f(v.w);
            *reinterpret_cast<float4*>(&es[drow][ecol4]) = e;
        }
        __syncthreads();
        #pragma unroll 8
        for (int d = 0; d < DK; ++d) {
            const float lx = lxs[r][d];
            const f2* ep = reinterpret_cast<const f2*>(&es[d][4 * c]);
            const f2 e0 = ep[0], e1 = ep[1];
            const f2 lx2 = {lx, lx};
            const f2 p0 = e0 * lx2, p1 = e1 * lx2;
            f2 t0, t1;
            t0.x = __builtin_amdgcn_exp2f(p0.x);
            t0.y = __builtin_amdgcn_exp2f(p0.y);
            t1.x = __builtin_amdgcn_exp2f(p1.x);
            t1.y = __builtin_amdgcn_exp2f(p1.y);
            acc0 += t0;
            acc1 += t1;
        }
        __syncthreads();
    }
    const float4 bv = *reinterpret_cast<const float4*>(&bias[u0 + 4 * c]);
    float4 o;
    o.x = fminf(fmaxf(acc0.x + bv.x, 0.f), 1.f);
    o.y = fminf(fmaxf(acc0.y + bv.y, 0.f), 1.f);
    o.z = fminf(fmaxf(acc1.x + bv.z, 0.f), 1.f);
    o.w = fminf(fmaxf(acc1.y + bv.w, 0.f), 1.f);
    *reinterpret_cast<float4*>(&out[(size_t)(b0 + r) * U + u0 + 4 * c]) = o;
}

extern "C" void kernel_launch(void* const* d_in, const int* in_sizes, int n_in,
                              void* d_out, int out_size, void* d_ws, size_t ws_size,
                              hipStream_t stream) {
    const float* x = (const float*)d_in[0];
    const float* w = (const float*)d_in[1];
    const float* b = (const float*)d_in[2];
    float* out = (float*)d_out;

    const int U = in_sizes[2];            // 512
    const int D = in_sizes[1] / U;        // 256
    const int B = in_sizes[0] / D;        // 2048

    const size_t need = ((size_t)B * D + (size_t)U * D) * sizeof(float);
    const bool ok = (ws_size >= need) && (B % 1024 == 0) && (D % 32 == 0) &&
                    (U % 32 == 0) && ((D / DR) % 2 == 0);
    if (!ok) {
        dim3 grid(U / UT, B / BT);
        fuzzy_fallback<<<grid, dim3(256), 0, stream>>>(x, w, b, out, B, D, U);
        return;
    }

    float* lxT = (float*)d_ws;            // [D][B]
    float* eT  = lxT + (size_t)B * D;     // [U][D]

    const int nblkA = (B / 32) * (D / 32) + (D / 32) * (U / 32);  // 640
    precompute_kernel<<<dim3(nblkA), dim3(256), 0, stream>>>(x, w, lxT, eT, B, D, U);

    dim3 grid(U / NU, B / 1024);          // (256, 2) = 512 blocks
    fuzzy_main<<<grid, dim3(256), 0, stream>>>(lxT, eT, b, out, B, D, U);
}

// Round 5
// 44.232 us; speedup vs baseline: 1.1293x; 1.0123x over previous
//
#include <hip/hip_runtime.h>

// y[b,u] = clip( sum_d x[b,d] ** exp2(w[d,u]) + bias[u], 0, 1 )
// inten = exp2( e[d,u] * lx[b,d] ),  e = exp2(w), lx = log2(x).
// R4: R2 was L1-pipe bound (per-lane vector loads of wave-uniform e),
//     R3 was latency-bound (2 waves/SIMD, compiler collapsed ping-pong).
//     Now: u0 block-uniform -> e via s_load (scalar pipe, zero L1 traffic);
//     lx row-major b128 loads; 4096 waves (4/SIMD); rolled chunk loop.
//     Trans floor 13.7us for 2.68e8 v_exp_f32.

#define NU 4    // u's per BLOCK (block-uniform => scalar loads for e)
#define DR 16   // d per chunk

typedef float f4 __attribute__((ext_vector_type(4)));

// ---- Kernel A: precompute ----
// lxr[b][d] = log2(x[b][d])  (row-major, same layout as x; elementwise)
// eT [u][d] = exp2(w[d][u])  (transposed so d is contiguous per u)
__global__ __launch_bounds__(256)
void precompute_kernel(const float* __restrict__ x, const float* __restrict__ w,
                       float* __restrict__ lxr, float* __restrict__ eT,
                       int B, int D, int U)
{
    __shared__ float t[32][33];
    const int tid = threadIdx.x;
    int blk = blockIdx.x;
    const int nlog = (B * D) / (256 * 4);          // f4 per thread
    if (blk < nlog) {
        const size_t i = ((size_t)blk * 256 + tid) * 4;
        const f4 v = *reinterpret_cast<const f4*>(x + i);
        f4 r;
        r.x = __builtin_amdgcn_logf(v.x);
        r.y = __builtin_amdgcn_logf(v.y);
        r.z = __builtin_amdgcn_logf(v.z);
        r.w = __builtin_amdgcn_logf(v.w);
        *reinterpret_cast<f4*>(lxr + i) = r;
    } else {
        blk -= nlog;
        const int row0 = tid >> 5;                  // 0..7
        const int col  = tid & 31;
        const int dt = blk / (U / 32);
        const int ut = blk % (U / 32);
        const int d0 = dt * 32, u0 = ut * 32;
        #pragma unroll
        for (int k = 0; k < 4; ++k) {
            const int r = row0 + k * 8;             // d within tile
            t[r][col] = __builtin_amdgcn_exp2f(w[(size_t)(d0 + r) * U + u0 + col]);
        }
        __syncthreads();
        #pragma unroll
        for (int k = 0; k < 4; ++k) {
            const int r = row0 + k * 8;             // u within tile
            eT[(size_t)(u0 + r) * D + d0 + col] = t[col][r];
        }
    }
}

// ---- Kernel B: main compute ----
// block: 256 threads, u0 = blockIdx.x*NU (uniform), thread -> one b.
__global__ __launch_bounds__(256)
void fuzzy_main(const float* __restrict__ lxr, const float* __restrict__ eT,
                const float* __restrict__ bias, float* __restrict__ out,
                int B, int D, int U)
{
    const int tid = threadIdx.x;
    const int u0  = blockIdx.x * NU;                // block-uniform
    const int b   = blockIdx.y * 256 + tid;

    const float* lxp = lxr + (size_t)b * D;
    const float* ebase = eT + (size_t)u0 * D;       // uniform pointer

    f4 acc[NU];
    #pragma unroll
    for (int j = 0; j < NU; ++j) acc[j] = (f4){0.f, 0.f, 0.f, 0.f};

    for (int c = 0; c < D; c += DR) {
        f4 lx[DR / 4];
        #pragma unroll
        for (int k = 0; k < DR / 4; ++k)
            lx[k] = *reinterpret_cast<const f4*>(lxp + c + 4 * k);

        #pragma unroll
        for (int j = 0; j < NU; ++j) {
            const float* ep = ebase + (size_t)j * D + c;   // uniform -> s_load
            #pragma unroll
            for (int k = 0; k < DR / 4; ++k) {
                const f4 e = *reinterpret_cast<const f4*>(ep + 4 * k);
                const f4 p = e * lx[k];             // v_mul (sgpr x vgpr)
                f4 t;
                t.x = __builtin_amdgcn_exp2f(p.x);
                t.y = __builtin_amdgcn_exp2f(p.y);
                t.z = __builtin_amdgcn_exp2f(p.z);
                t.w = __builtin_amdgcn_exp2f(p.w);
                acc[j] += t;                        // v_pk_add_f32
            }
        }
    }

    #pragma unroll
    for (int j = 0; j < NU; ++j) {
        const float s = (acc[j].x + acc[j].y) + (acc[j].z + acc[j].w);
        const float o = fminf(fmaxf(s + bias[u0 + j], 0.f), 1.f);
        out[(size_t)b * U + u0 + j] = o;
    }
}

// ---- Fallback (R1 kernel) for odd shapes / small ws ----
#define BT 32
#define UT 32
#define DK 64
typedef float f2 __attribute__((ext_vector_type(2)));
__global__ __launch_bounds__(256)
void fuzzy_fallback(const float* __restrict__ x, const float* __restrict__ w,
                    const float* __restrict__ bias, float* __restrict__ out,
                    int B, int D, int U)
{
    __shared__ float lxs[BT][DK + 1];
    __shared__ float es[DK][UT];
    const int tid = threadIdx.x;
    const int c = tid & 7;
    const int r = tid >> 3;
    const int u0 = blockIdx.x * UT;
    const int b0 = blockIdx.y * BT;
    f2 acc0 = {0.f, 0.f}, acc1 = {0.f, 0.f};
    const int lrow = tid >> 4, lcol4 = (tid & 15) * 4;
    const int erow = tid >> 3, ecol4 = (tid & 7) * 4;
    for (int d0 = 0; d0 < D; d0 += DK) {
        #pragma unroll
        for (int p = 0; p < BT / 16; ++p) {
            const int row = p * 16 + lrow;
            const float4 v = *reinterpret_cast<const float4*>(
                &x[(size_t)(b0 + row) * D + d0 + lcol4]);
            lxs[row][lcol4 + 0] = __builtin_amdgcn_logf(v.x);
            lxs[row][lcol4 + 1] = __builtin_amdgcn_logf(v.y);
            lxs[row][lcol4 + 2] = __builtin_amdgcn_logf(v.z);
            lxs[row][lcol4 + 3] = __builtin_amdgcn_logf(v.w);
        }
        #pragma unroll
        for (int p = 0; p < DK / 32; ++p) {
            const int drow = p * 32 + erow;
            const float4 v = *reinterpret_cast<const float4*>(
                &w[(size_t)(d0 + drow) * U + u0 + ecol4]);
            float4 e;
            e.x = __builtin_amdgcn_exp2f(v.x);
            e.y = __builtin_amdgcn_exp2f(v.y);
            e.z = __builtin_amdgcn_exp2f(v.z);
            e.w = __builtin_amdgcn_exp2f(v.w);
            *reinterpret_cast<float4*>(&es[drow][ecol4]) = e;
        }
        __syncthreads();
        #pragma unroll 8
        for (int d = 0; d < DK; ++d) {
            const float lx = lxs[r][d];
            const f2* ep = reinterpret_cast<const f2*>(&es[d][4 * c]);
            const f2 e0 = ep[0], e1 = ep[1];
            const f2 lx2 = {lx, lx};
            const f2 p0 = e0 * lx2, p1 = e1 * lx2;
            f2 t0, t1;
            t0.x = __builtin_amdgcn_exp2f(p0.x);
            t0.y = __builtin_amdgcn_exp2f(p0.y);
            t1.x = __builtin_amdgcn_exp2f(p1.x);
            t1.y = __builtin_amdgcn_exp2f(p1.y);
            acc0 += t0;
            acc1 += t1;
        }
        __syncthreads();
    }
    const float4 bv = *reinterpret_cast<const float4*>(&bias[u0 + 4 * c]);
    float4 o;
    o.x = fminf(fmaxf(acc0.x + bv.x, 0.f), 1.f);
    o.y = fminf(fmaxf(acc0.y + bv.y, 0.f), 1.f);
    o.z = fminf(fmaxf(acc1.x + bv.z, 0.f), 1.f);
    o.w = fminf(fmaxf(acc1.y + bv.w, 0.f), 1.f);
    *reinterpret_cast<float4*>(&out[(size_t)(b0 + r) * U + u0 + 4 * c]) = o;
}

extern "C" void kernel_launch(void* const* d_in, const int* in_sizes, int n_in,
                              void* d_out, int out_size, void* d_ws, size_t ws_size,
                              hipStream_t stream) {
    const float* x = (const float*)d_in[0];
    const float* w = (const float*)d_in[1];
    const float* b = (const float*)d_in[2];
    float* out = (float*)d_out;

    const int U = in_sizes[2];            // 512
    const int D = in_sizes[1] / U;        // 256
    const int B = in_sizes[0] / D;        // 2048

    const size_t need = ((size_t)B * D + (size_t)U * D) * sizeof(float);
    const bool ok = (ws_size >= need) && (B % 256 == 0) && (D % 32 == 0) &&
                    (U % 32 == 0) && ((B * D) % 1024 == 0) && (D % DR == 0) &&
                    (U % NU == 0);
    if (!ok) {
        dim3 grid(U / UT, B / BT);
        fuzzy_fallback<<<grid, dim3(256), 0, stream>>>(x, w, b, out, B, D, U);
        return;
    }

    float* lxr = (float*)d_ws;            // [B][D] row-major
    float* eT  = lxr + (size_t)B * D;     // [U][D]

    const int nblkA = (B * D) / 1024 + (D / 32) * (U / 32);   // 512 + 128
    precompute_kernel<<<dim3(nblkA), dim3(256), 0, stream>>>(x, w, lxr, eT, B, D, U);

    dim3 grid(U / NU, B / 256);           // (128, 8) = 1024 blocks
    fuzzy_main<<<grid, dim3(256), 0, stream>>>(lxr, eT, b, out, B, D, U);
}